// Round 6
// baseline (122.125 us; speedup 1.0000x reference)
//
#include <hip/hip_runtime.h>
#include <stdint.h>

// BinaryTreeLogicNet: out = sigmoid(tree_gcd(sigmoid(x @ W^T - 2)) * w_out + b_out)
// M=65536 rows, L=256 leaves.
// R6: R5's coalesced-x experiment, race-fixed.
//   - R5 failed (absmax 1.56e-2): strip LDS RAW had no compiler-visible
//     ordering (TBAA: short4 writes vs short8 reads may "not alias" -> reorder).
//     Fix: asm memory clobbers around strip ops; HW DS is in-order per wave.
//   - Double strip (group0/group1) kills the intra-iteration WAR.
//   - Chunk-major strip, 144B/chunk: ds_write_b128 (conflict-free, 16B aligned),
//     ds_read2_b64 reads (uniform banks). Main loop: zero global, zero cvt.
//   - x preamble: 32 contiguous coalesced 1KB wave-loads -> bf16 regs (C8[16]).
// 512 thr = 8 waves, 1 block/CU (154 KB LDS), ONE barrier.

#define EPS 1e-6f
#define LOG2E 1.44269504088896340736f
#define WSTR 264                 // shorts per W row (256 + 8 pad)
#define WIMG_SHORTS (256 * WSTR)
#define XSTR 144                 // bytes per chunk slot in A-strip

typedef __attribute__((ext_vector_type(8))) short short8;
typedef __attribute__((ext_vector_type(4))) short short4_t;
typedef __attribute__((ext_vector_type(4))) float float4_t;
typedef __attribute__((ext_vector_type(4))) unsigned int uint4_t;

__device__ __forceinline__ float fast_sigmoid(float z) {
    float e = __builtin_amdgcn_exp2f(-z * LOG2E);
    return __builtin_amdgcn_rcpf(1.0f + e);
}

__device__ __forceinline__ short f2bf(float f) {   // fp32 -> bf16 RNE
    uint32_t u = __builtin_bit_cast(uint32_t, f);
    u += 0x7FFFu + ((u >> 16) & 1u);
    return (short)(u >> 16);
}

__device__ __forceinline__ short8 pack8(float4 a, float4 b) {
    short8 s;
    s[0] = f2bf(a.x); s[1] = f2bf(a.y); s[2] = f2bf(a.z); s[3] = f2bf(a.w);
    s[4] = f2bf(b.x); s[5] = f2bf(b.y); s[6] = f2bf(b.z); s[7] = f2bf(b.w);
    return s;
}

__device__ __forceinline__ float ggcd(float l, float r, float lam) {
    float a = fabsf(l) + EPS;
    float b = fabsf(r) + EPS;
    float mn = fminf(a, b);
    float mx = fmaxf(a, b);
    return fmaf(lam, mn - mx, mx);   // lam*mn + (1-lam)*mx
}

// tree levels 1-4 on one 16-acc row-group; acc consumed in place
__device__ __forceinline__ void tree_reduce(float4_t acc[16], int c0,
                                            const float4* pv, float res[4]) {
    #pragma unroll
    for (int t = 0; t < 16; ++t) {
        #pragma unroll
        for (int r = 0; r < 4; ++r) acc[t][r] = fast_sigmoid(acc[t][r] - 2.0f);
    }
    #pragma unroll
    for (int tp = 0; tp < 8; ++tp) {          // level 1 (off 0)
        float4 p = pv[c0 * 8 + tp];
        #pragma unroll
        for (int r = 0; r < 4; ++r)
            acc[tp][r] = ggcd(acc[2*tp][r] * p.x, acc[2*tp+1][r] * p.y, p.z);
    }
    #pragma unroll
    for (int tp = 0; tp < 4; ++tp) {          // level 2 (off 128)
        float4 p = pv[128 + c0 * 4 + tp];
        #pragma unroll
        for (int r = 0; r < 4; ++r)
            acc[tp][r] = ggcd(acc[2*tp][r] * p.x, acc[2*tp+1][r] * p.y, p.z);
    }
    #pragma unroll
    for (int tp = 0; tp < 2; ++tp) {          // level 3 (off 192)
        float4 p = pv[192 + c0 * 2 + tp];
        #pragma unroll
        for (int r = 0; r < 4; ++r)
            acc[tp][r] = ggcd(acc[2*tp][r] * p.x, acc[2*tp+1][r] * p.y, p.z);
    }
    {                                          // level 4 (off 224)
        float4 p = pv[224 + c0];
        #pragma unroll
        for (int r = 0; r < 4; ++r)
            res[r] = ggcd(acc[0][r] * p.x, acc[1][r] * p.y, p.z);
    }
}

__global__ __launch_bounds__(512, 2)
void btln_fused(const float* __restrict__ x, const float* __restrict__ Wl,
                const float* __restrict__ wts, const float* __restrict__ bia,
                const float* __restrict__ wout, const float* __restrict__ bout,
                float* __restrict__ out) {
    __shared__ short Ws[WIMG_SHORTS];          // 135168 B
    __shared__ float4 pv[256];                 // 4096 B (w0,w1,lam)
    __shared__ char Xs[8 * 2 * 8 * XSTR];      // 18432 B: 8 waves x 2 strips x 8 chunks

    const int tid  = threadIdx.x;
    const int lane = tid & 63;
    const int wv   = tid >> 6;                 // wave 0..7
    const int c0   = lane & 15;
    const int q    = lane >> 4;
    const int band = lane >> 3;                // which kt this lane's chunks feed
    const int jj   = lane & 7;                 // chunk index within kt

    const int rowbase = blockIdx.x * 256 + wv * 32;

    // ---- x preamble: 32 contiguous coalesced 1KB wave-loads, cvt to bf16.
    //      C8[i] = rows (2i, 2i+1), k-chunk [4*lane, 4*lane+4) each half. ----
    const float4* xb = (const float4*)(x + (size_t)rowbase * 256);
    short8 C8[16];
    {
        float4 R[16];
        #pragma unroll
        for (int i = 0; i < 16; ++i) R[i] = xb[i * 64 + lane];
        #pragma unroll
        for (int i = 0; i < 8; ++i) C8[i] = pack8(R[2*i], R[2*i+1]);
        #pragma unroll
        for (int i = 0; i < 16; ++i) R[i] = xb[(16 + i) * 64 + lane];
        #pragma unroll
        for (int i = 0; i < 8; ++i) C8[8 + i] = pack8(R[2*i], R[2*i+1]);
    }

    // ---- stage W: fp32 -> bf16, nibble-swap row permute ----
    {
        const float4* Wv4 = (const float4*)Wl;
        #pragma unroll 4
        for (int it = 0; it < 32; ++it) {
            int i   = it * 512 + tid;          // float4 index (= j*64+kc4)
            int j   = i >> 6;
            int kc4 = i & 63;
            float4 w4 = Wv4[i];
            int p = ((j & 15) << 4) | (j >> 4);
            short4_t s4;
            s4.x = f2bf(w4.x); s4.y = f2bf(w4.y); s4.z = f2bf(w4.z); s4.w = f2bf(w4.w);
            *(short4_t*)&Ws[p * WSTR + kc4 * 4] = s4;
        }
    }
    if (tid < 255)
        pv[tid] = make_float4(wts[2 * tid], wts[2 * tid + 1], fast_sigmoid(bia[tid]), 0.f);
    __syncthreads();                           // the ONLY barrier

    // ---- GEMM main loop: no global loads, no converts ----
    char* strip0 = &Xs[wv * (2 * 8 * XSTR)];
    char* strip1 = strip0 + 8 * XSTR;

    float4_t acc0[16], acc1[16];
    #pragma unroll
    for (int t = 0; t < 16; ++t) {
        acc0[t] = (float4_t){0.f, 0.f, 0.f, 0.f};
        acc1[t] = (float4_t){0.f, 0.f, 0.f, 0.f};
    }

    #pragma unroll 1
    for (int kt = 0; kt < 8; ++kt) {
        // owning lanes (band==kt) deposit this kt's 32-k slab, chunk-major:
        // chunk jj at byte jj*XSTR, rows pairs as 16B ds_write_b128
        if (band == kt) {
            char* s0 = strip0 + jj * XSTR;
            char* s1 = strip1 + jj * XSTR;
            #pragma unroll
            for (int i = 0; i < 8; ++i) {
                *(short8*)(s0 + i * 16) = C8[i];
                *(short8*)(s1 + i * 16) = C8[8 + i];
            }
        }
        asm volatile("" ::: "memory");   // forbid read hoist; HW DS in-order per wave
        // af: row c0, k-local [8q, 8q+8) = chunks 2q, 2q+1 at row offset c0*8
        const char* r0 = strip0 + (2 * q) * XSTR + c0 * 8;
        const char* r1 = strip1 + (2 * q) * XSTR + c0 * 8;
        uint2 lo0 = *(const uint2*)r0;
        uint2 hi0 = *(const uint2*)(r0 + XSTR);
        uint2 lo1 = *(const uint2*)r1;
        uint2 hi1 = *(const uint2*)(r1 + XSTR);
        asm volatile("" ::: "memory");   // forbid next-kt write sink above reads
        short8 af0 = __builtin_bit_cast(short8, (uint4_t){lo0.x, lo0.y, hi0.x, hi0.y});
        short8 af1 = __builtin_bit_cast(short8, (uint4_t){lo1.x, lo1.y, hi1.x, hi1.y});

        const int kk = kt * 32;
        #pragma unroll
        for (int t = 0; t < 16; ++t) {
            short8 bf = *(const short8*)&Ws[(t * 16 + c0) * WSTR + kk + q * 8];
            acc0[t] = __builtin_amdgcn_mfma_f32_16x16x32_bf16(af0, bf, acc0[t], 0, 0, 0);
            acc1[t] = __builtin_amdgcn_mfma_f32_16x16x32_bf16(af1, bf, acc1[t], 0, 0, 0);
        }
    }

    // ---- epilogue ----
    float res0[4], res1[4];
    tree_reduce(acc0, c0, pv, res0);
    tree_reduce(acc1, c0, pv, res1);

    const int offs[4] = {240, 248, 252, 254};
    #pragma unroll
    for (int k = 0; k < 4; ++k) {
        float4 p = pv[offs[k] + (c0 >> (k + 1))];
        bool isLeft = ((c0 >> k) & 1) == 0;
        #pragma unroll
        for (int r = 0; r < 4; ++r) {
            float o0 = __shfl_xor(res0[r], 1 << k, 64);
            float o1 = __shfl_xor(res1[r], 1 << k, 64);
            float lf0 = isLeft ? res0[r] : o0, rt0 = isLeft ? o0 : res0[r];
            float lf1 = isLeft ? res1[r] : o1, rt1 = isLeft ? o1 : res1[r];
            res0[r] = ggcd(lf0 * p.x, rt0 * p.y, p.z);
            res1[r] = ggcd(lf1 * p.x, rt1 * p.y, p.z);
        }
    }

    if (c0 == 0) {
        const float wo = wout[0];
        const float bo = bout[0];
        #pragma unroll
        for (int r = 0; r < 4; ++r) {
            out[rowbase + q * 4 + r]      = fast_sigmoid(fmaf(res0[r], wo, bo));
            out[rowbase + 16 + q * 4 + r] = fast_sigmoid(fmaf(res1[r], wo, bo));
        }
    }
}

extern "C" void kernel_launch(void* const* d_in, const int* in_sizes, int n_in,
                              void* d_out, int out_size, void* d_ws, size_t ws_size,
                              hipStream_t stream) {
    const float* x   = (const float*)d_in[0];
    const float* Wl  = (const float*)d_in[1];
    const float* wts = (const float*)d_in[2];
    const float* bia = (const float*)d_in[3];
    const float* wo  = (const float*)d_in[4];
    const float* bo  = (const float*)d_in[5];
    float* out = (float*)d_out;

    const int rows = out_size;               // 65536
    dim3 grid(rows / 256), block(512);       // 256 blocks x 8 waves, 1 block/CU
    btln_fused<<<grid, block, 0, stream>>>(x, Wl, wts, bia, wo, bo, out);
}

// Round 7
// 113.743 us; speedup vs baseline: 1.0737x; 1.0737x over previous
//
#include <hip/hip_runtime.h>
#include <stdint.h>

// BinaryTreeLogicNet: out = sigmoid(tree_gcd(sigmoid(x @ W^T - 2)) * w_out + b_out)
// M=65536 rows, L=256 leaves.
// R7: attack the vector-memory delivery path (the R2-R6 invariant).
//   - Pre-kernel: W -> 128 KB bf16 image in d_ws, nibble-swap row permute,
//     16B-chunk XOR swizzle baked in (pos = chunk ^ (row&7)) so the MFMA
//     B-frag ds_read_b128 pattern is 2-way bank-free with NO padding
//     (global_load_lds requires contiguous lane x 16B placement).
//   - Main: 512 thr (8 waves x 16 rows = 128 rows/block), 512 blocks,
//     2 blocks/CU (LDS 68 KB), 16 waves/CU. W K-tiles (4 x 32 KB) streamed
//     via global_load_lds DOUBLE-BUFFERED: issue kt+1, compute kt, barrier.
//     A-frags gathered global->VGPR one tile ahead (16-seg gathers, full
//     cache-line use). Per-CU global bytes: x 256 KB + W 256 KB bf16 (L2-fast)
//     vs R2-R6's 512 KB with fp32 W and shallow MLP.
//   - Tree epilogue identical to R4 (verified: absmax 0.00390625).

#define EPS 1e-6f
#define LOG2E 1.44269504088896340736f
#define PARAM_OFF 131072            // byte offset of param table in img

typedef __attribute__((ext_vector_type(8))) short short8;
typedef __attribute__((ext_vector_type(4))) short short4_t;
typedef __attribute__((ext_vector_type(4))) float float4_t;

__device__ __forceinline__ float fast_sigmoid(float z) {
    float e = __builtin_amdgcn_exp2f(-z * LOG2E);
    return __builtin_amdgcn_rcpf(1.0f + e);
}

__device__ __forceinline__ short f2bf(float f) {   // fp32 -> bf16 RNE
    uint32_t u = __builtin_bit_cast(uint32_t, f);
    u += 0x7FFFu + ((u >> 16) & 1u);
    return (short)(u >> 16);
}

__device__ __forceinline__ short8 pack8(float4 a, float4 b) {
    short8 s;
    s[0] = f2bf(a.x); s[1] = f2bf(a.y); s[2] = f2bf(a.z); s[3] = f2bf(a.w);
    s[4] = f2bf(b.x); s[5] = f2bf(b.y); s[6] = f2bf(b.z); s[7] = f2bf(b.w);
    return s;
}

__device__ __forceinline__ float ggcd(float l, float r, float lam) {
    float a = fabsf(l) + EPS;
    float b = fabsf(r) + EPS;
    float mn = fminf(a, b);
    float mx = fmaxf(a, b);
    return fmaf(lam, mn - mx, mx);   // lam*mn + (1-lam)*mx
}

__device__ __forceinline__ void lds16(const void* g, void* l) {
    __builtin_amdgcn_global_load_lds(
        (const __attribute__((address_space(1))) unsigned int*)g,
        (__attribute__((address_space(3))) unsigned int*)l, 16, 0, 0);
}

// tree levels 1-4 on one 16-acc row-group; acc consumed in place
__device__ __forceinline__ void tree_reduce(float4_t acc[16], int c0,
                                            const float4* pv, float res[4]) {
    #pragma unroll
    for (int t = 0; t < 16; ++t) {
        #pragma unroll
        for (int r = 0; r < 4; ++r) acc[t][r] = fast_sigmoid(acc[t][r] - 2.0f);
    }
    #pragma unroll
    for (int tp = 0; tp < 8; ++tp) {          // level 1 (off 0)
        float4 p = pv[c0 * 8 + tp];
        #pragma unroll
        for (int r = 0; r < 4; ++r)
            acc[tp][r] = ggcd(acc[2*tp][r] * p.x, acc[2*tp+1][r] * p.y, p.z);
    }
    #pragma unroll
    for (int tp = 0; tp < 4; ++tp) {          // level 2 (off 128)
        float4 p = pv[128 + c0 * 4 + tp];
        #pragma unroll
        for (int r = 0; r < 4; ++r)
            acc[tp][r] = ggcd(acc[2*tp][r] * p.x, acc[2*tp+1][r] * p.y, p.z);
    }
    #pragma unroll
    for (int tp = 0; tp < 2; ++tp) {          // level 3 (off 192)
        float4 p = pv[192 + c0 * 2 + tp];
        #pragma unroll
        for (int r = 0; r < 4; ++r)
            acc[tp][r] = ggcd(acc[2*tp][r] * p.x, acc[2*tp+1][r] * p.y, p.z);
    }
    {                                          // level 4 (off 224)
        float4 p = pv[224 + c0];
        #pragma unroll
        for (int r = 0; r < 4; ++r)
            res[r] = ggcd(acc[0][r] * p.x, acc[1][r] * p.y, p.z);
    }
}

// ---- pre-kernel: build swizzled bf16 W image + packed params in d_ws ----
// img byte a (a = kt*32768 + j*128 + cpos*16 + h*8):
//   holds W[swap(j)][kt*64 + (cpos^(j&7))*8 + h*4 .. +4) as bf16x4
__global__ __launch_bounds__(256)
void convert_w(const float* __restrict__ Wl, const float* __restrict__ wts,
               const float* __restrict__ bia, char* __restrict__ img) {
    int i = blockIdx.x * 256 + threadIdx.x;   // 64 blocks -> 16384 threads x 8 B
    int a = i * 8;
    int kt   = a >> 15;
    int s    = a & 32767;
    int j    = s >> 7;
    int b    = s & 127;
    int cpos = b >> 4;
    int h    = (b >> 3) & 1;
    int c    = cpos ^ (j & 7);
    int k    = kt * 64 + c * 8 + h * 4;
    int src  = ((j & 15) << 4) | (j >> 4);    // nibble-swap (involution)
    float4 w4 = *(const float4*)&Wl[src * 256 + k];
    short4_t s4;
    s4.x = f2bf(w4.x); s4.y = f2bf(w4.y); s4.z = f2bf(w4.z); s4.w = f2bf(w4.w);
    *(short4_t*)&img[a] = s4;

    if (i < 255) {
        float4* pv = (float4*)(img + PARAM_OFF);
        pv[i] = make_float4(wts[2 * i], wts[2 * i + 1], fast_sigmoid(bia[i]), 0.f);
    } else if (i == 255) {
        ((float4*)(img + PARAM_OFF))[255] = make_float4(0.f, 0.f, 0.f, 0.f);
    }
}

// ---- main kernel ----
__global__ __launch_bounds__(512, 4)
void btln_main(const float* __restrict__ x, const char* __restrict__ img,
               const float* __restrict__ wout, const float* __restrict__ bout,
               float* __restrict__ out) {
    __shared__ short Wt[2][16384];           // 2 x 32 KB W K-tiles
    __shared__ float4 pv[256];               // 4 KB packed (w0,w1,lam)

    const int tid  = threadIdx.x;
    const int lane = tid & 63;
    const int wv   = tid >> 6;               // wave 0..7
    const int c0   = lane & 15;
    const int q    = lane >> 4;

    if (tid < 256) pv[tid] = ((const float4*)(img + PARAM_OFF))[tid];

    // issue tile 0 (wave wv owns 4 KB: 4 x (64 lanes x 16 B))
    {
        const char* g = img + wv * 4096 + lane * 16;
        char* l = (char*)&Wt[0][wv * 2048];
        #pragma unroll
        for (int it = 0; it < 4; ++it)
            lds16(g + it * 1024, l + it * 1024);
    }

    const int rowbase = blockIdx.x * 128 + wv * 16;
    const float* xr = x + (size_t)(rowbase + c0) * 256;

    float4_t acc[16];
    #pragma unroll
    for (int t = 0; t < 16; ++t) acc[t] = (float4_t){0.f, 0.f, 0.f, 0.f};

    // A-frags for tile 0 (frag-layout gather: lane(c0,q) <- row c0, k q*8..)
    float4 a0 = *(const float4*)(xr + q * 8);
    float4 a1 = *(const float4*)(xr + q * 8 + 4);
    float4 a2 = *(const float4*)(xr + 32 + q * 8);
    float4 a3 = *(const float4*)(xr + 32 + q * 8 + 4);

    __syncthreads();                          // tile 0 resident (vmcnt drained)

    const int vx = c0 & 7;
    #pragma unroll 1
    for (int kt = 0; kt < 4; ++kt) {
        const short* cur = Wt[kt & 1];
        if (kt < 3) {                         // issue tile kt+1 into other buffer
            const char* g = img + (kt + 1) * 32768 + wv * 4096 + lane * 16;
            char* l = (char*)&Wt[(kt + 1) & 1][wv * 2048];
            #pragma unroll
            for (int it = 0; it < 4; ++it)
                lds16(g + it * 1024, l + it * 1024);
        }
        // prefetch next tile's A-frags (kt=3: redundant reload, harmless)
        const int kn = (kt < 3 ? kt + 1 : 3) * 64;
        float4 b0 = *(const float4*)(xr + kn + q * 8);
        float4 b1 = *(const float4*)(xr + kn + q * 8 + 4);
        float4 b2 = *(const float4*)(xr + kn + 32 + q * 8);
        float4 b3 = *(const float4*)(xr + kn + 32 + q * 8 + 4);

        short8 af0 = pack8(a0, a1);           // k-local q*8..q*8+7
        short8 af1 = pack8(a2, a3);           // k-local 32+q*8..
        #pragma unroll
        for (int t = 0; t < 16; ++t) {
            const short* base = &cur[(t * 16 + c0) * 64];
            short8 bf0 = *(const short8*)&base[(q ^ vx) * 8];        // chunk q
            short8 bf1 = *(const short8*)&base[((q + 4) ^ vx) * 8];  // chunk q+4
            acc[t] = __builtin_amdgcn_mfma_f32_16x16x32_bf16(af0, bf0, acc[t], 0, 0, 0);
            acc[t] = __builtin_amdgcn_mfma_f32_16x16x32_bf16(af1, bf1, acc[t], 0, 0, 0);
        }
        __syncthreads();                      // tile kt consumed; kt+1 landed
        a0 = b0; a1 = b1; a2 = b2; a3 = b3;
    }

    // ---- epilogue: leaf sigmoid + tree (acc[t][r]: row q*4+r, leaf c0*16+t) ----
    float res[4];
    tree_reduce(acc, c0, pv, res);

    const int offs[4] = {240, 248, 252, 254};
    #pragma unroll
    for (int k = 0; k < 4; ++k) {             // levels 5-8: butterfly across c0
        float4 p = pv[offs[k] + (c0 >> (k + 1))];
        bool isLeft = ((c0 >> k) & 1) == 0;
        #pragma unroll
        for (int r = 0; r < 4; ++r) {
            float other = __shfl_xor(res[r], 1 << k, 64);
            float lf = isLeft ? res[r] : other;
            float rt = isLeft ? other  : res[r];
            res[r] = ggcd(lf * p.x, rt * p.y, p.z);
        }
    }

    if (c0 == 0) {
        const float wo = wout[0];
        const float bo = bout[0];
        #pragma unroll
        for (int r = 0; r < 4; ++r)
            out[rowbase + q * 4 + r] = fast_sigmoid(fmaf(res[r], wo, bo));
    }
}

extern "C" void kernel_launch(void* const* d_in, const int* in_sizes, int n_in,
                              void* d_out, int out_size, void* d_ws, size_t ws_size,
                              hipStream_t stream) {
    const float* x   = (const float*)d_in[0];
    const float* Wl  = (const float*)d_in[1];
    const float* wts = (const float*)d_in[2];
    const float* bia = (const float*)d_in[3];
    const float* wo  = (const float*)d_in[4];
    const float* bo  = (const float*)d_in[5];
    float* out = (float*)d_out;
    char* img = (char*)d_ws;                  // 128 KB W image + 4 KB params

    convert_w<<<dim3(64), dim3(256), 0, stream>>>(Wl, wts, bia, img);

    const int rows = out_size;                // 65536
    dim3 grid(rows / 128), block(512);        // 512 blocks x 8 waves, 2 blocks/CU
    btln_main<<<grid, block, 0, stream>>>(x, img, wo, bo, out);
}